// Round 1
// baseline (328.795 us; speedup 1.0000x reference)
//
#include <hip/hip_runtime.h>
#include <hip/hip_bf16.h>
#include <stdint.h>

// ---------- types ----------
typedef __attribute__((ext_vector_type(4))) float f32x4;
typedef __attribute__((ext_vector_type(8))) short bf16x8;

__device__ __forceinline__ unsigned short f2bf(float f) {
  union { float f; unsigned u; } v; v.f = f;
  unsigned r = v.u + 0x7fffu + ((v.u >> 16) & 1u);  // RNE
  return (unsigned short)(r >> 16);
}

// async global->LDS, 16B per lane; lds arg must be wave-uniform base
#define GLL16(g, l)                                                   \
  __builtin_amdgcn_global_load_lds(                                   \
      (__attribute__((address_space(1))) void*)(g),                   \
      (__attribute__((address_space(3))) void*)(l), 16, 0, 0)

// ---------- convert x fp32 -> bf16 ----------
__global__ __launch_bounds__(256) void k_conv_x(const float* __restrict__ x,
                                                unsigned short* __restrict__ xb) {
  int i = blockIdx.x * 256 + threadIdx.x;     // one float4 per thread
  float4 v = ((const float4*)x)[i];
  ushort4 o;
  o.x = f2bf(v.x); o.y = f2bf(v.y); o.z = f2bf(v.z); o.w = f2bf(v.w);
  ((ushort4*)xb)[i] = o;
}

// ---------- convert + transpose weights: WT[t][n][k] = w_t[k][n] ----------
__global__ __launch_bounds__(256) void k_conv_wT(const float* __restrict__ wq,
                                                 const float* __restrict__ wk,
                                                 const float* __restrict__ wv,
                                                 const float* __restrict__ wo,
                                                 unsigned short* __restrict__ WT) {
  __shared__ unsigned short tile[32][33];
  int t = blockIdx.z;
  const float* w = (t == 0) ? wq : (t == 1) ? wk : (t == 2) ? wv : wo;
  int k0 = blockIdx.x * 32, n0 = blockIdx.y * 32;
  int tx = threadIdx.x, ty = threadIdx.y;   // 32 x 8
#pragma unroll
  for (int s = 0; s < 32; s += 8)
    tile[tx][ty + s] = f2bf(w[(size_t)(k0 + ty + s) * 768 + n0 + tx]);
  __syncthreads();
#pragma unroll
  for (int s = 0; s < 32; s += 8)
    WT[(size_t)t * 589824 + (size_t)(n0 + ty + s) * 768 + k0 + tx] = tile[ty + s][tx];
}

// ---------- QKV projection: out = (Xb @ W + bias) * scale, bf16 out ----------
__global__ __launch_bounds__(256) void k_gemm_qkv(const unsigned short* __restrict__ Xb,
                                                  const unsigned short* __restrict__ WT,
                                                  const float* __restrict__ bq,
                                                  const float* __restrict__ bk_,
                                                  const float* __restrict__ bv,
                                                  unsigned short* __restrict__ Q,
                                                  unsigned short* __restrict__ K,
                                                  unsigned short* __restrict__ V,
                                                  float qscale) {
  __shared__ __align__(16) unsigned short As[128 * 32];  // [row][k] 64B rows
  __shared__ __align__(16) unsigned short Bs[128 * 32];  // [n][k]   64B rows
  const int tid = threadIdx.x, lane = tid & 63, w = tid >> 6;
  const int bid = blockIdx.x;
  const int nt = bid % 18, mt = bid / 18;
  const int m0 = mt * 128;
  const int ng = nt * 128;
  const int t = ng / 768, n0 = ng % 768;
  const unsigned short* Wt = WT + (size_t)t * 589824;
  const float* bias = (t == 0) ? bq : (t == 1) ? bk_ : bv;
  unsigned short* Out = (t == 0) ? Q : (t == 1) ? K : V;
  const float scale = (t == 0) ? qscale : 1.0f;

  const int wm = w >> 1, wn = w & 1;
  const int rl4 = lane >> 2, cb4 = (lane & 3) * 16;
  const int fr = lane & 15, kb = (lane >> 4) * 16;

  f32x4 acc[4][4];
#pragma unroll
  for (int a = 0; a < 4; ++a)
#pragma unroll
    for (int b = 0; b < 4; ++b) acc[a][b] = (f32x4){0.f, 0.f, 0.f, 0.f};

  for (int k0 = 0; k0 < 768; k0 += 32) {
    __syncthreads();
#pragma unroll
    for (int c = 0; c < 2; ++c) {
      int row = w * 32 + c * 16 + rl4;
      GLL16((const char*)Xb + (size_t)(m0 + row) * 1536 + k0 * 2 + cb4,
            (char*)As + w * 2048 + c * 1024);
      GLL16((const char*)Wt + (size_t)(n0 + row) * 1536 + k0 * 2 + cb4,
            (char*)Bs + w * 2048 + c * 1024);
    }
    __syncthreads();
    bf16x8 af[4], bfr[4];
#pragma unroll
    for (int fm = 0; fm < 4; ++fm)
      af[fm] = *(const bf16x8*)((const char*)As + (wm * 64 + fm * 16 + fr) * 64 + kb);
#pragma unroll
    for (int fn = 0; fn < 4; ++fn)
      bfr[fn] = *(const bf16x8*)((const char*)Bs + (wn * 64 + fn * 16 + fr) * 64 + kb);
#pragma unroll
    for (int fm = 0; fm < 4; ++fm)
#pragma unroll
      for (int fn = 0; fn < 4; ++fn)
        acc[fm][fn] = __builtin_amdgcn_mfma_f32_16x16x32_bf16(af[fm], bfr[fn],
                                                              acc[fm][fn], 0, 0, 0);
  }

  const int rowb = (lane >> 4) * 4;
#pragma unroll
  for (int fm = 0; fm < 4; ++fm)
#pragma unroll
    for (int fn = 0; fn < 4; ++fn) {
      int col = n0 + wn * 64 + fn * 16 + fr;
      float b = bias[col];
#pragma unroll
      for (int rg = 0; rg < 4; ++rg) {
        int rowg = m0 + wm * 64 + fm * 16 + rowb + rg;
        Out[(size_t)rowg * 768 + col] = f2bf((acc[fm][fn][rg] + b) * scale);
      }
    }
}

// ---------- attention logits: logits[h,i,j] += sum_{r in split, d} q*k ----------
__global__ __launch_bounds__(256) void k_attn(const unsigned short* __restrict__ Q,
                                              const unsigned short* __restrict__ Kb,
                                              float* __restrict__ logits) {
  __shared__ __align__(16) unsigned short As[128 * 64];  // [i][d] 128B rows
  __shared__ __align__(16) unsigned short Bs[128 * 64];  // [j][d] 128B rows
  const int tid = threadIdx.x, lane = tid & 63, w = tid >> 6;
  const int bid = blockIdx.x;
  const int tile = bid & 3;
  const int h = (bid >> 2) % 12;
  const int rs = bid / 48;
  const int i0 = (tile >> 1) * 128, j0 = (tile & 1) * 128;
  const int wm = w >> 1, wn = w & 1;
  const int rl8 = lane >> 3, cb8 = (lane & 7) * 16;
  const int fr = lane & 15, kb = (lane >> 4) * 16;

  f32x4 acc[4][4];
#pragma unroll
  for (int a = 0; a < 4; ++a)
#pragma unroll
    for (int b = 0; b < 4; ++b) acc[a][b] = (f32x4){0.f, 0.f, 0.f, 0.f};

  for (int rr = 0; rr < 16; ++rr) {
    int r = rs * 16 + rr;
    __syncthreads();
#pragma unroll
    for (int c = 0; c < 4; ++c) {
      int row = w * 32 + c * 8 + rl8;
      GLL16((const char*)Q + (size_t)(r * 256 + i0 + row) * 1536 + h * 128 + cb8,
            (char*)As + w * 4096 + c * 1024);
      GLL16((const char*)Kb + (size_t)(r * 256 + j0 + row) * 1536 + h * 128 + cb8,
            (char*)Bs + w * 4096 + c * 1024);
    }
    __syncthreads();
#pragma unroll
    for (int kk = 0; kk < 2; ++kk) {
      bf16x8 af[4], bfr[4];
#pragma unroll
      for (int fm = 0; fm < 4; ++fm)
        af[fm] = *(const bf16x8*)((const char*)As + (wm * 64 + fm * 16 + fr) * 128 + kk * 64 + kb);
#pragma unroll
      for (int fn = 0; fn < 4; ++fn)
        bfr[fn] = *(const bf16x8*)((const char*)Bs + (wn * 64 + fn * 16 + fr) * 128 + kk * 64 + kb);
#pragma unroll
      for (int fm = 0; fm < 4; ++fm)
#pragma unroll
        for (int fn = 0; fn < 4; ++fn)
          acc[fm][fn] = __builtin_amdgcn_mfma_f32_16x16x32_bf16(af[fm], bfr[fn],
                                                                acc[fm][fn], 0, 0, 0);
    }
  }

  float* lg = logits + (size_t)h * 65536;
  const int rowb = (lane >> 4) * 4;
#pragma unroll
  for (int fm = 0; fm < 4; ++fm)
#pragma unroll
    for (int fn = 0; fn < 4; ++fn) {
      int jj = j0 + wn * 64 + fn * 16 + fr;
#pragma unroll
      for (int rg = 0; rg < 4; ++rg) {
        int ii = i0 + wm * 64 + fm * 16 + rowb + rg;
        atomicAdd(&lg[ii * 256 + jj], acc[fm][fn][rg]);
      }
    }
}

// ---------- softmax over j; write fp32 to d_out and bf16 to ws ----------
__global__ __launch_bounds__(256) void k_softmax(const float* __restrict__ lg,
                                                 float* __restrict__ pout,
                                                 unsigned short* __restrict__ pbf) {
  const int row = blockIdx.x;          // h*256 + i
  const int j = threadIdx.x;
  const int lane = j & 63, wv = j >> 6;
  float v = lg[(size_t)row * 256 + j];
  float m = v;
#pragma unroll
  for (int o = 32; o; o >>= 1) m = fmaxf(m, __shfl_xor(m, o, 64));
  __shared__ float sm[4], ss[4];
  if (lane == 0) sm[wv] = m;
  __syncthreads();
  m = fmaxf(fmaxf(sm[0], sm[1]), fmaxf(sm[2], sm[3]));
  float e = __expf(v - m);
  float s = e;
#pragma unroll
  for (int o = 32; o; o >>= 1) s += __shfl_xor(s, o, 64);
  if (lane == 0) ss[wv] = s;
  __syncthreads();
  s = ss[0] + ss[1] + ss[2] + ss[3];
  float p = e / s;
  pout[(size_t)row * 256 + j] = p;
  pbf[(size_t)row * 256 + j] = f2bf(p);
}

// ---------- PV: context[r*256+i, h*64+d] = sum_j P[h,i,j] * V[r*256+j, h*64+d] ----------
__global__ __launch_bounds__(256) void k_pv(const unsigned short* __restrict__ P,
                                            const unsigned short* __restrict__ V,
                                            unsigned short* __restrict__ Cb) {
  __shared__ __align__(16) unsigned short Ps[256 * 32];  // [i][j] 64B rows
  __shared__ __align__(16) unsigned short Vs[32 * 64];   // [j][d] 128B rows
  const int tid = threadIdx.x, lane = tid & 63, w = tid >> 6;
  const int bid = blockIdx.x;
  const int h = bid % 12, r = bid / 12;
  const int fr = lane & 15, kb = (lane >> 4) * 16;
  const int rl4 = lane >> 2, cb4 = (lane & 3) * 16;
  const int rl8 = lane >> 3, cb8 = (lane & 7) * 16;

  f32x4 acc[4][4];
#pragma unroll
  for (int a = 0; a < 4; ++a)
#pragma unroll
    for (int b = 0; b < 4; ++b) acc[a][b] = (f32x4){0.f, 0.f, 0.f, 0.f};

  const char* Ph = (const char*)P + (size_t)h * 131072;
  for (int j0 = 0; j0 < 256; j0 += 32) {
    __syncthreads();
#pragma unroll
    for (int c = 0; c < 4; ++c) {
      int row = w * 64 + c * 16 + rl4;
      GLL16(Ph + (size_t)row * 512 + j0 * 2 + cb4, (char*)Ps + w * 4096 + c * 1024);
    }
    {
      int row = w * 8 + rl8;
      GLL16((const char*)V + (size_t)(r * 256 + j0 + row) * 1536 + h * 128 + cb8,
            (char*)Vs + w * 1024);
    }
    __syncthreads();
    bf16x8 af[4];
#pragma unroll
    for (int fm = 0; fm < 4; ++fm)
      af[fm] = *(const bf16x8*)((const char*)Ps + (w * 64 + fm * 16 + fr) * 64 + kb);
#pragma unroll
    for (int fn = 0; fn < 4; ++fn) {
      bf16x8 bvv;
#pragma unroll
      for (int e = 0; e < 8; ++e)
        bvv[e] = (short)Vs[(8 * (lane >> 4) + e) * 64 + fn * 16 + fr];
#pragma unroll
      for (int fm = 0; fm < 4; ++fm)
        acc[fm][fn] = __builtin_amdgcn_mfma_f32_16x16x32_bf16(af[fm], bvv,
                                                              acc[fm][fn], 0, 0, 0);
    }
  }

  const int rowb = (lane >> 4) * 4;
#pragma unroll
  for (int fm = 0; fm < 4; ++fm)
#pragma unroll
    for (int fn = 0; fn < 4; ++fn) {
      int col = h * 64 + fn * 16 + fr;
#pragma unroll
      for (int rg = 0; rg < 4; ++rg) {
        int m = r * 256 + w * 64 + fm * 16 + rowb + rg;
        Cb[(size_t)m * 768 + col] = f2bf(acc[fm][fn][rg]);
      }
    }
}

// ---------- output projection: out = Cb @ wo + bo (fp32 out) ----------
__global__ __launch_bounds__(256) void k_gemm_out(const unsigned short* __restrict__ Cb,
                                                  const unsigned short* __restrict__ WTo,
                                                  const float* __restrict__ bo,
                                                  float* __restrict__ Outp) {
  __shared__ __align__(16) unsigned short As[128 * 32];
  __shared__ __align__(16) unsigned short Bs[128 * 32];
  const int tid = threadIdx.x, lane = tid & 63, w = tid >> 6;
  const int bid = blockIdx.x;
  const int nt = bid % 6, mt = bid / 6;
  const int m0 = mt * 128, n0 = nt * 128;
  const int wm = w >> 1, wn = w & 1;
  const int rl4 = lane >> 2, cb4 = (lane & 3) * 16;
  const int fr = lane & 15, kb = (lane >> 4) * 16;

  f32x4 acc[4][4];
#pragma unroll
  for (int a = 0; a < 4; ++a)
#pragma unroll
    for (int b = 0; b < 4; ++b) acc[a][b] = (f32x4){0.f, 0.f, 0.f, 0.f};

  for (int k0 = 0; k0 < 768; k0 += 32) {
    __syncthreads();
#pragma unroll
    for (int c = 0; c < 2; ++c) {
      int row = w * 32 + c * 16 + rl4;
      GLL16((const char*)Cb + (size_t)(m0 + row) * 1536 + k0 * 2 + cb4,
            (char*)As + w * 2048 + c * 1024);
      GLL16((const char*)WTo + (size_t)(n0 + row) * 1536 + k0 * 2 + cb4,
            (char*)Bs + w * 2048 + c * 1024);
    }
    __syncthreads();
    bf16x8 af[4], bfr[4];
#pragma unroll
    for (int fm = 0; fm < 4; ++fm)
      af[fm] = *(const bf16x8*)((const char*)As + (wm * 64 + fm * 16 + fr) * 64 + kb);
#pragma unroll
    for (int fn = 0; fn < 4; ++fn)
      bfr[fn] = *(const bf16x8*)((const char*)Bs + (wn * 64 + fn * 16 + fr) * 64 + kb);
#pragma unroll
    for (int fm = 0; fm < 4; ++fm)
#pragma unroll
      for (int fn = 0; fn < 4; ++fn)
        acc[fm][fn] = __builtin_amdgcn_mfma_f32_16x16x32_bf16(af[fm], bfr[fn],
                                                              acc[fm][fn], 0, 0, 0);
  }

  const int rowb = (lane >> 4) * 4;
#pragma unroll
  for (int fm = 0; fm < 4; ++fm)
#pragma unroll
    for (int fn = 0; fn < 4; ++fn) {
      int col = n0 + wn * 64 + fn * 16 + fr;
      float b = bo[col];
#pragma unroll
      for (int rg = 0; rg < 4; ++rg) {
        int rowg = m0 + wm * 64 + fm * 16 + rowb + rg;
        Outp[(size_t)rowg * 768 + col] = acc[fm][fn][rg] + b;
      }
    }
}

// ---------- launch ----------
extern "C" void kernel_launch(void* const* d_in, const int* in_sizes, int n_in,
                              void* d_out, int out_size, void* d_ws, size_t ws_size,
                              hipStream_t stream) {
  const float* x  = (const float*)d_in[0];
  const float* wq = (const float*)d_in[1];
  const float* bq = (const float*)d_in[2];
  const float* wk = (const float*)d_in[3];
  const float* bk = (const float*)d_in[4];
  const float* wv = (const float*)d_in[5];
  const float* bv = (const float*)d_in[6];
  const float* wo = (const float*)d_in[7];
  const float* bo = (const float*)d_in[8];
  float* out = (float*)d_out;

  char* wsb = (char*)d_ws;
  unsigned short* Cb = (unsigned short*)(wsb + 0);           // Xb, later context
  unsigned short* Qb = (unsigned short*)(wsb + 50331648);
  unsigned short* Kb = (unsigned short*)(wsb + 100663296);
  unsigned short* Vb = (unsigned short*)(wsb + 150994944);
  unsigned short* WT = (unsigned short*)(wsb + 201326592);   // 4x768x768 bf16
  float*          Lg = (float*)(wsb + 206045184);            // 12x256x256 f32
  unsigned short* Pb = (unsigned short*)(wsb + 209190912);   // 12x256x256 bf16

  const float qscale = 0.011048543456039806f;  // (1/8)/sqrt(128)

  k_conv_x<<<24576, 256, 0, stream>>>(x, Cb);
  k_conv_wT<<<dim3(24, 24, 4), dim3(32, 8), 0, stream>>>(wq, wk, wv, wo, WT);
  k_gemm_qkv<<<4608, 256, 0, stream>>>(Cb, WT, bq, bk, bv, Qb, Kb, Vb, qscale);
  hipMemsetAsync(Lg, 0, (size_t)12 * 256 * 256 * 4, stream);
  k_attn<<<384, 256, 0, stream>>>(Qb, Kb, Lg);
  k_softmax<<<3072, 256, 0, stream>>>(Lg, out + 25165824, Pb);
  k_pv<<<1536, 256, 0, stream>>>(Pb, Vb, Cb);
  k_gemm_out<<<1536, 256, 0, stream>>>(Cb, WT + (size_t)3 * 589824, bo, out);
}

// Round 2
// 286.171 us; speedup vs baseline: 1.1489x; 1.1489x over previous
//
#include <hip/hip_runtime.h>
#include <hip/hip_bf16.h>
#include <stdint.h>

// ---------- types ----------
typedef __attribute__((ext_vector_type(4))) float f32x4;
typedef __attribute__((ext_vector_type(8))) short bf16x8;

__device__ __forceinline__ unsigned short f2bf(float f) {
  union { float f; unsigned u; } v; v.f = f;
  unsigned r = v.u + 0x7fffu + ((v.u >> 16) & 1u);  // RNE
  return (unsigned short)(r >> 16);
}

// async global->LDS, 16B per lane; lds arg must be wave-uniform base
#define GLL16(g, l)                                                   \
  __builtin_amdgcn_global_load_lds(                                   \
      (__attribute__((address_space(1))) void*)(g),                   \
      (__attribute__((address_space(3))) void*)(l), 16, 0, 0)

// ---------- convert x fp32 -> bf16 ----------
__global__ __launch_bounds__(256) void k_conv_x(const float* __restrict__ x,
                                                unsigned short* __restrict__ xb) {
  int i = blockIdx.x * 256 + threadIdx.x;     // one float4 per thread
  float4 v = ((const float4*)x)[i];
  ushort4 o;
  o.x = f2bf(v.x); o.y = f2bf(v.y); o.z = f2bf(v.z); o.w = f2bf(v.w);
  ((ushort4*)xb)[i] = o;
}

// ---------- convert + transpose weights: WT[t][n][k] = w_t[k][n] ----------
__global__ __launch_bounds__(256) void k_conv_wT(const float* __restrict__ wq,
                                                 const float* __restrict__ wk,
                                                 const float* __restrict__ wv,
                                                 const float* __restrict__ wo,
                                                 unsigned short* __restrict__ WT) {
  __shared__ unsigned short tile[32][33];
  int t = blockIdx.z;
  const float* w = (t == 0) ? wq : (t == 1) ? wk : (t == 2) ? wv : wo;
  int k0 = blockIdx.x * 32, n0 = blockIdx.y * 32;
  int tx = threadIdx.x, ty = threadIdx.y;   // 32 x 8
#pragma unroll
  for (int s = 0; s < 32; s += 8)
    tile[tx][ty + s] = f2bf(w[(size_t)(k0 + ty + s) * 768 + n0 + tx]);
  __syncthreads();
#pragma unroll
  for (int s = 0; s < 32; s += 8)
    WT[(size_t)t * 589824 + (size_t)(n0 + ty + s) * 768 + k0 + tx] = tile[ty + s][tx];
}

// ---------- 256x256 GEMM core: 4-deep ring, counted vmcnt, swizzled LDS ----------
// A panel: Ag + row*1536 bytes (row = m-tile row 0..255), K = 768 (24 tiles of 32)
// B panel: Bg + row*1536 bytes (row = n-tile row 0..255), stored [n][k]
// lds: 128 KiB = 4 slots x (A 16K + B 16K). Swizzle: 16B-slot ^= ((row>>1)&3).
__device__ __forceinline__ void gemm256_core(const char* __restrict__ Ag,
                                             const char* __restrict__ Bg,
                                             char* lds, int tid,
                                             f32x4 (&acc)[8][4]) {
  const int lane = tid & 63, w = tid >> 6;
  const int wm = w >> 2, wn = w & 3;
  const int fr = lane & 15, kb = (lane >> 4) * 16;
  // staging role: waves 0-3 stage A rows 64w..64w+63; waves 4-7 stage B rows
  const bool stageB = (w >= 4);
  const char* Sg = stageB ? Bg : Ag;
  const int wrow0 = 64 * (w & 3);
  const int srow = lane >> 2;        // 0..15 within 1KB chunk
  const int slotL = lane & 3;        // linear 16B slot within 64B row

  // prologue: stage tiles 0,1,2
#pragma unroll
  for (int t = 0; t < 3; ++t) {
    char* dslot = lds + t * 32768 + (stageB ? 16384 : 0);
#pragma unroll
    for (int c = 0; c < 4; ++c) {
      int row = wrow0 + c * 16 + srow;
      int sG = slotL ^ ((row >> 1) & 3);
      GLL16(Sg + (size_t)row * 1536 + t * 64 + sG * 16,
            dslot + (wrow0 + c * 16) * 64);
    }
  }

  for (int t = 0; t < 24; ++t) {
    if (t < 22)       asm volatile("s_waitcnt vmcnt(8)" ::: "memory");
    else if (t == 22) asm volatile("s_waitcnt vmcnt(4)" ::: "memory");
    else              asm volatile("s_waitcnt vmcnt(0)" ::: "memory");
    __builtin_amdgcn_s_barrier();

    const char* slot = lds + (t & 3) * 32768;
    bf16x8 af[8], bfr[4];
#pragma unroll
    for (int fm = 0; fm < 8; ++fm) {
      int row = wm * 128 + fm * 16 + fr;
      af[fm] = *(const bf16x8*)(slot + row * 64 + (kb ^ (((row >> 1) & 3) << 4)));
    }
#pragma unroll
    for (int fn = 0; fn < 4; ++fn) {
      int row = wn * 64 + fn * 16 + fr;
      bfr[fn] = *(const bf16x8*)(slot + 16384 + row * 64 + (kb ^ (((row >> 1) & 3) << 4)));
    }

    if (t + 3 < 24) {  // stage tile t+3 into slot (t+3)&3 (last read at tile t-1)
      char* dslot = lds + ((t + 3) & 3) * 32768 + (stageB ? 16384 : 0);
#pragma unroll
      for (int c = 0; c < 4; ++c) {
        int row = wrow0 + c * 16 + srow;
        int sG = slotL ^ ((row >> 1) & 3);
        GLL16(Sg + (size_t)row * 1536 + (t + 3) * 64 + sG * 16,
              dslot + (wrow0 + c * 16) * 64);
      }
    }

    __builtin_amdgcn_s_setprio(1);
#pragma unroll
    for (int fm = 0; fm < 8; ++fm)
#pragma unroll
      for (int fn = 0; fn < 4; ++fn)
        acc[fm][fn] = __builtin_amdgcn_mfma_f32_16x16x32_bf16(af[fm], bfr[fn],
                                                              acc[fm][fn], 0, 0, 0);
    __builtin_amdgcn_s_setprio(0);
  }
}

// ---------- QKV projection: 256x256 tiles ----------
__global__ __launch_bounds__(512, 1) void k_gemm_qkv(const unsigned short* __restrict__ Xb,
                                                     const unsigned short* __restrict__ WT,
                                                     const float* __restrict__ bq,
                                                     const float* __restrict__ bk_,
                                                     const float* __restrict__ bv,
                                                     unsigned short* __restrict__ Q,
                                                     unsigned short* __restrict__ K,
                                                     unsigned short* __restrict__ V,
                                                     float qscale) {
  __shared__ __align__(16) char lds[131072];
  const int tid = threadIdx.x, lane = tid & 63, w = tid >> 6;
  // XCD swizzle: grid 1152 = 8 x 144 -> each XCD gets 16 consecutive m-panels
  const int bid = blockIdx.x;
  const int swz = (bid & 7) * 144 + (bid >> 3);
  const int mt = swz / 9, nt = swz % 9;
  const int m0 = mt * 256;
  const int t = nt / 3, n0 = (nt % 3) * 256;

  const unsigned short* Wt = WT + (size_t)t * 589824;
  const float* bias = (t == 0) ? bq : (t == 1) ? bk_ : bv;
  unsigned short* Out = (t == 0) ? Q : (t == 1) ? K : V;
  const float scale = (t == 0) ? qscale : 1.0f;

  f32x4 acc[8][4];
#pragma unroll
  for (int a = 0; a < 8; ++a)
#pragma unroll
    for (int b = 0; b < 4; ++b) acc[a][b] = (f32x4){0.f, 0.f, 0.f, 0.f};

  gemm256_core((const char*)Xb + (size_t)m0 * 1536,
               (const char*)Wt + (size_t)n0 * 1536, lds, tid, acc);

  const int wm = w >> 2, wn = w & 3;
  const int fr = lane & 15, rowb = (lane >> 4) * 4;
#pragma unroll
  for (int fm = 0; fm < 8; ++fm)
#pragma unroll
    for (int fn = 0; fn < 4; ++fn) {
      int col = n0 + wn * 64 + fn * 16 + fr;
      float b = bias[col];
#pragma unroll
      for (int rg = 0; rg < 4; ++rg) {
        int row = m0 + wm * 128 + fm * 16 + rowb + rg;
        Out[(size_t)row * 768 + col] = f2bf((acc[fm][fn][rg] + b) * scale);
      }
    }
}

// ---------- output projection: 256x256 tiles, fp32 out ----------
__global__ __launch_bounds__(512, 1) void k_gemm_out(const unsigned short* __restrict__ Cb,
                                                     const unsigned short* __restrict__ WTo,
                                                     const float* __restrict__ bo,
                                                     float* __restrict__ Outp) {
  __shared__ __align__(16) char lds[131072];
  const int tid = threadIdx.x, lane = tid & 63, w = tid >> 6;
  const int bid = blockIdx.x;   // grid 384 = 8 x 48
  const int swz = (bid & 7) * 48 + (bid >> 3);
  const int mt = swz / 3, nt = swz % 3;
  const int m0 = mt * 256, n0 = nt * 256;

  f32x4 acc[8][4];
#pragma unroll
  for (int a = 0; a < 8; ++a)
#pragma unroll
    for (int b = 0; b < 4; ++b) acc[a][b] = (f32x4){0.f, 0.f, 0.f, 0.f};

  gemm256_core((const char*)Cb + (size_t)m0 * 1536,
               (const char*)WTo + (size_t)n0 * 1536, lds, tid, acc);

  const int wm = w >> 2, wn = w & 3;
  const int fr = lane & 15, rowb = (lane >> 4) * 4;
#pragma unroll
  for (int fm = 0; fm < 8; ++fm)
#pragma unroll
    for (int fn = 0; fn < 4; ++fn) {
      int col = n0 + wn * 64 + fn * 16 + fr;
      float b = bo[col];
#pragma unroll
      for (int rg = 0; rg < 4; ++rg) {
        int row = m0 + wm * 128 + fm * 16 + rowb + rg;
        Outp[(size_t)row * 768 + col] = acc[fm][fn][rg] + b;
      }
    }
}

// ---------- attention logits: logits[h,i,j] += sum_{r in split, d} q*k ----------
__global__ __launch_bounds__(256) void k_attn(const unsigned short* __restrict__ Q,
                                              const unsigned short* __restrict__ Kb,
                                              float* __restrict__ logits) {
  __shared__ __align__(16) unsigned short As[128 * 64];  // [i][d] 128B rows
  __shared__ __align__(16) unsigned short Bs[128 * 64];  // [j][d] 128B rows
  const int tid = threadIdx.x, lane = tid & 63, w = tid >> 6;
  const int bid = blockIdx.x;
  const int tile = bid & 3;
  const int h = (bid >> 2) % 12;
  const int rs = bid / 48;
  const int i0 = (tile >> 1) * 128, j0 = (tile & 1) * 128;
  const int wm = w >> 1, wn = w & 1;
  const int rl8 = lane >> 3, cb8 = (lane & 7) * 16;
  const int fr = lane & 15, kb = (lane >> 4) * 16;

  f32x4 acc[4][4];
#pragma unroll
  for (int a = 0; a < 4; ++a)
#pragma unroll
    for (int b = 0; b < 4; ++b) acc[a][b] = (f32x4){0.f, 0.f, 0.f, 0.f};

  for (int rr = 0; rr < 16; ++rr) {
    int r = rs * 16 + rr;
    __syncthreads();
#pragma unroll
    for (int c = 0; c < 4; ++c) {
      int row = w * 32 + c * 8 + rl8;
      GLL16((const char*)Q + (size_t)(r * 256 + i0 + row) * 1536 + h * 128 + cb8,
            (char*)As + w * 4096 + c * 1024);
      GLL16((const char*)Kb + (size_t)(r * 256 + j0 + row) * 1536 + h * 128 + cb8,
            (char*)Bs + w * 4096 + c * 1024);
    }
    __syncthreads();
#pragma unroll
    for (int kk = 0; kk < 2; ++kk) {
      bf16x8 af[4], bfr[4];
#pragma unroll
      for (int fm = 0; fm < 4; ++fm)
        af[fm] = *(const bf16x8*)((const char*)As + (wm * 64 + fm * 16 + fr) * 128 + kk * 64 + kb);
#pragma unroll
      for (int fn = 0; fn < 4; ++fn)
        bfr[fn] = *(const bf16x8*)((const char*)Bs + (wn * 64 + fn * 16 + fr) * 128 + kk * 64 + kb);
#pragma unroll
      for (int fm = 0; fm < 4; ++fm)
#pragma unroll
        for (int fn = 0; fn < 4; ++fn)
          acc[fm][fn] = __builtin_amdgcn_mfma_f32_16x16x32_bf16(af[fm], bfr[fn],
                                                                acc[fm][fn], 0, 0, 0);
    }
  }

  float* lg = logits + (size_t)h * 65536;
  const int rowb = (lane >> 4) * 4;
#pragma unroll
  for (int fm = 0; fm < 4; ++fm)
#pragma unroll
    for (int fn = 0; fn < 4; ++fn) {
      int jj = j0 + wn * 64 + fn * 16 + fr;
#pragma unroll
      for (int rg = 0; rg < 4; ++rg) {
        int ii = i0 + wm * 64 + fm * 16 + rowb + rg;
        atomicAdd(&lg[ii * 256 + jj], acc[fm][fn][rg]);
      }
    }
}

// ---------- softmax over j; write fp32 to d_out and bf16 to ws ----------
__global__ __launch_bounds__(256) void k_softmax(const float* __restrict__ lg,
                                                 float* __restrict__ pout,
                                                 unsigned short* __restrict__ pbf) {
  const int row = blockIdx.x;          // h*256 + i
  const int j = threadIdx.x;
  const int lane = j & 63, wv = j >> 6;
  float v = lg[(size_t)row * 256 + j];
  float m = v;
#pragma unroll
  for (int o = 32; o; o >>= 1) m = fmaxf(m, __shfl_xor(m, o, 64));
  __shared__ float sm[4], ss[4];
  if (lane == 0) sm[wv] = m;
  __syncthreads();
  m = fmaxf(fmaxf(sm[0], sm[1]), fmaxf(sm[2], sm[3]));
  float e = __expf(v - m);
  float s = e;
#pragma unroll
  for (int o = 32; o; o >>= 1) s += __shfl_xor(s, o, 64);
  if (lane == 0) ss[wv] = s;
  __syncthreads();
  s = ss[0] + ss[1] + ss[2] + ss[3];
  float p = e / s;
  pout[(size_t)row * 256 + j] = p;
  pbf[(size_t)row * 256 + j] = f2bf(p);
}

// ---------- PV: context[r*256+i, h*64+d] = sum_j P[h,i,j] * V[r*256+j, h*64+d] ----------
__global__ __launch_bounds__(256) void k_pv(const unsigned short* __restrict__ P,
                                            const unsigned short* __restrict__ V,
                                            unsigned short* __restrict__ Cb) {
  __shared__ __align__(16) unsigned short Ps[256 * 32];  // [i][j] 64B rows
  __shared__ __align__(16) unsigned short Vs[32 * 64];   // [j][d] 128B rows
  const int tid = threadIdx.x, lane = tid & 63, w = tid >> 6;
  const int bid = blockIdx.x;
  const int h = bid % 12, r = bid / 12;
  const int fr = lane & 15, kb = (lane >> 4) * 16;
  const int rl4 = lane >> 2, cb4 = (lane & 3) * 16;
  const int rl8 = lane >> 3, cb8 = (lane & 7) * 16;

  f32x4 acc[4][4];
#pragma unroll
  for (int a = 0; a < 4; ++a)
#pragma unroll
    for (int b = 0; b < 4; ++b) acc[a][b] = (f32x4){0.f, 0.f, 0.f, 0.f};

  const char* Ph = (const char*)P + (size_t)h * 131072;
  for (int j0 = 0; j0 < 256; j0 += 32) {
    __syncthreads();
#pragma unroll
    for (int c = 0; c < 4; ++c) {
      int row = w * 64 + c * 16 + rl4;
      GLL16(Ph + (size_t)row * 512 + j0 * 2 + cb4, (char*)Ps + w * 4096 + c * 1024);
    }
    {
      int row = w * 8 + rl8;
      GLL16((const char*)V + (size_t)(r * 256 + j0 + row) * 1536 + h * 128 + cb8,
            (char*)Vs + w * 1024);
    }
    __syncthreads();
    bf16x8 af[4];
#pragma unroll
    for (int fm = 0; fm < 4; ++fm)
      af[fm] = *(const bf16x8*)((const char*)Ps + (w * 64 + fm * 16 + fr) * 64 + kb);
#pragma unroll
    for (int fn = 0; fn < 4; ++fn) {
      bf16x8 bvv;
#pragma unroll
      for (int e = 0; e < 8; ++e)
        bvv[e] = (short)Vs[(8 * (lane >> 4) + e) * 64 + fn * 16 + fr];
#pragma unroll
      for (int fm = 0; fm < 4; ++fm)
        acc[fm][fn] = __builtin_amdgcn_mfma_f32_16x16x32_bf16(af[fm], bvv,
                                                              acc[fm][fn], 0, 0, 0);
    }
  }

  const int rowb = (lane >> 4) * 4;
#pragma unroll
  for (int fm = 0; fm < 4; ++fm)
#pragma unroll
    for (int fn = 0; fn < 4; ++fn) {
      int col = h * 64 + fn * 16 + fr;
#pragma unroll
      for (int rg = 0; rg < 4; ++rg) {
        int m = r * 256 + w * 64 + fm * 16 + rowb + rg;
        Cb[(size_t)m * 768 + col] = f2bf(acc[fm][fn][rg]);
      }
    }
}

// ---------- launch ----------
extern "C" void kernel_launch(void* const* d_in, const int* in_sizes, int n_in,
                              void* d_out, int out_size, void* d_ws, size_t ws_size,
                              hipStream_t stream) {
  const float* x  = (const float*)d_in[0];
  const float* wq = (const float*)d_in[1];
  const float* bq = (const float*)d_in[2];
  const float* wk = (const float*)d_in[3];
  const float* bk = (const float*)d_in[4];
  const float* wv = (const float*)d_in[5];
  const float* bv = (const float*)d_in[6];
  const float* wo = (const float*)d_in[7];
  const float* bo = (const float*)d_in[8];
  float* out = (float*)d_out;

  char* wsb = (char*)d_ws;
  unsigned short* Cb = (unsigned short*)(wsb + 0);           // Xb, later context
  unsigned short* Qb = (unsigned short*)(wsb + 50331648);
  unsigned short* Kb = (unsigned short*)(wsb + 100663296);
  unsigned short* Vb = (unsigned short*)(wsb + 150994944);
  unsigned short* WT = (unsigned short*)(wsb + 201326592);   // 4x768x768 bf16
  float*          Lg = (float*)(wsb + 206045184);            // 12x256x256 f32
  unsigned short* Pb = (unsigned short*)(wsb + 209190912);   // 12x256x256 bf16

  const float qscale = 0.011048543456039806f;  // (1/8)/sqrt(128)

  k_conv_x<<<24576, 256, 0, stream>>>(x, Cb);
  k_conv_wT<<<dim3(24, 24, 4), dim3(32, 8), 0, stream>>>(wq, wk, wv, wo, WT);
  k_gemm_qkv<<<1152, 512, 0, stream>>>(Cb, WT, bq, bk, bv, Qb, Kb, Vb, qscale);
  hipMemsetAsync(Lg, 0, (size_t)12 * 256 * 256 * 4, stream);
  k_attn<<<384, 256, 0, stream>>>(Qb, Kb, Lg);
  k_softmax<<<3072, 256, 0, stream>>>(Lg, out + 25165824, Pb);
  k_pv<<<1536, 256, 0, stream>>>(Pb, Vb, Cb);
  k_gemm_out<<<384, 512, 0, stream>>>(Cb, WT + (size_t)3 * 589824, bo, out);
}